// Round 1
// baseline (202.501 us; speedup 1.0000x reference)
//
#include <hip/hip_runtime.h>
#include <hip/hip_bf16.h>

// ---------- types ----------
typedef __attribute__((ext_vector_type(8))) short  short8;
typedef __attribute__((ext_vector_type(4))) short  short4v;
typedef __attribute__((ext_vector_type(4))) float  f32x4;

#define NCLS 10
#define TILE 256
#define NW   10           // waves per block (one class per wave)
#define TPB  (NW * 64)    // 640 threads

// fp32 -> bf16 round-to-nearest-even
static __device__ inline unsigned short f2bf(float x) {
    unsigned u = __builtin_bit_cast(unsigned, x);
    unsigned r = (u + 0x7FFFu + ((u >> 16) & 1u)) >> 16;
    return (unsigned short)r;
}

// swizzled element index into the transposed LDS tile [64][256] bf16
static __device__ inline int lds_elem(int d, int row) {
    return d * 256 + ((((row >> 3) ^ ((d >> 1) & 7))) << 3) + (row & 7);
}

// ---------- kernel 1: per-class counts ----------
__global__ void HL_hist(const int* __restrict__ yhat, int* __restrict__ counts, int N) {
    __shared__ int lh[NCLS];
    if (threadIdx.x < NCLS) lh[threadIdx.x] = 0;
    __syncthreads();
    long stride = (long)gridDim.x * blockDim.x;
    for (long i = (long)blockIdx.x * blockDim.x + threadIdx.x; i < N; i += stride)
        atomicAdd(&lh[yhat[i]], 1);
    __syncthreads();
    if (threadIdx.x < NCLS) atomicAdd(&counts[threadIdx.x], lh[threadIdx.x]);
}

// ---------- kernel 2: masked Grams via MFMA ----------
// grams: [NCLS][64][64] f32, pre-zeroed.
__global__ void HL_gram(const float* __restrict__ h, const int* __restrict__ yhat,
                        float* __restrict__ grams, int N, int ntiles) {
    __shared__ __align__(16) unsigned short hs[64 * 256]; // transposed + swizzled bf16 tile
    __shared__ __align__(16) int ysh[TILE];

    const int tid  = threadIdx.x;
    const int wid  = tid >> 6;     // class this wave owns
    const int lane = tid & 63;

    f32x4 acc[4][4];
#pragma unroll
    for (int i = 0; i < 4; ++i)
#pragma unroll
        for (int j = 0; j < 4; ++j) acc[i][j] = (f32x4){0.f, 0.f, 0.f, 0.f};

    for (int t = blockIdx.x; t < ntiles; t += gridDim.x) {
        const long base = (long)t * TILE;

        // ---- stage yhat ----
        for (int r = tid; r < TILE; r += TPB) {
            long g = base + r;
            ysh[r] = (g < N) ? yhat[g] : -1;
        }
        // ---- stage h (transpose fp32->bf16 into swizzled LDS) ----
        // unit u: 4 rows x 4 cols;  r4 = u>>4 (0..63), d4 = (u&15)*4
        for (int u = tid; u < (TILE / 4) * 16; u += TPB) {
            const int r4 = u >> 4;
            const int d4 = (u & 15) << 2;
            f32x4 v[4];
#pragma unroll
            for (int j = 0; j < 4; ++j) {
                long g = base + 4 * r4 + j;
                if (g < N) v[j] = *reinterpret_cast<const f32x4*>(h + g * 64 + d4);
                else       v[j] = (f32x4){0.f, 0.f, 0.f, 0.f};
            }
#pragma unroll
            for (int q = 0; q < 4; ++q) {
                const int d = d4 + q;
                short4v pk;
                pk[0] = (short)f2bf(v[0][q]);
                pk[1] = (short)f2bf(v[1][q]);
                pk[2] = (short)f2bf(v[2][q]);
                pk[3] = (short)f2bf(v[3][q]);
                const int e = lds_elem(d, 4 * r4);
                *reinterpret_cast<short4v*>(&hs[e]) = pk;
            }
        }
        __syncthreads();

        // ---- compute: wave `wid` accumulates its class Gram over this tile ----
        for (int ks = 0; ks < TILE / 32; ++ks) {
            const int krow = ks * 32 + ((lane >> 4) << 3); // this lane's 8 k-rows
            short8 mask;
#pragma unroll
            for (int j = 0; j < 8; ++j)
                mask[j] = (ysh[krow + j] == wid) ? (short)0xFFFF : (short)0;

            short8 raw[4], am[4];
#pragma unroll
            for (int nb = 0; nb < 4; ++nb) {
                const int d = nb * 16 + (lane & 15);
                const int e = lds_elem(d, krow); // krow&7==0
                raw[nb] = *reinterpret_cast<const short8*>(&hs[e]);
                am[nb]  = raw[nb] & mask;
            }
#pragma unroll
            for (int mb = 0; mb < 4; ++mb)
#pragma unroll
                for (int nb = 0; nb < 4; ++nb)
                    acc[mb][nb] = __builtin_amdgcn_mfma_f32_16x16x32_bf16(
                        am[mb], raw[nb], acc[mb][nb], 0, 0, 0);
        }
        __syncthreads(); // protect LDS before next tile's overwrite
    }

    // ---- epilogue: atomic-accumulate this wave's class Gram ----
    float* g = grams + wid * 64 * 64;
#pragma unroll
    for (int mb = 0; mb < 4; ++mb)
#pragma unroll
        for (int nb = 0; nb < 4; ++nb)
#pragma unroll
            for (int r = 0; r < 4; ++r) {
                const int row = mb * 16 + ((lane >> 4) << 2) + r;
                const int col = nb * 16 + (lane & 15);
                atomicAdd(&g[row * 64 + col], acc[mb][nb][r]);
            }
}

// ---------- kernel 3: M = 0.5*G/count + I; loss += 0.5*logdet via Cholesky ----------
__global__ void HL_chol(const float* __restrict__ grams, const int* __restrict__ counts,
                        float* __restrict__ out) {
    __shared__ float M[64][65];
    __shared__ float lcol[64];
    const int cls = blockIdx.x;
    const int i   = threadIdx.x; // 0..63, one wave

    const float inv = 0.5f / (float)counts[cls];
    const float* g  = grams + cls * 64 * 64;
    for (int c = 0; c < 64; ++c)
        M[i][c] = g[i * 64 + c] * inv + (i == c ? 1.0f : 0.0f);

    float slog = 0.0f;
    for (int j = 0; j < 64; ++j) {
        __syncthreads();
        const float pivotsq = M[j][j];
        const float pivot   = sqrtf(pivotsq);
        lcol[i] = M[i][j] / pivot;
        if (i == 0) slog += logf(pivotsq);
        __syncthreads();
        if (i > j) {
            const float lij = lcol[i];
            for (int c = j + 1; c <= i; ++c) M[i][c] -= lij * lcol[c];
        }
    }
    if (i == 0) atomicAdd(out, 0.5f * slog);
}

// ---------- launcher ----------
extern "C" void kernel_launch(void* const* d_in, const int* in_sizes, int n_in,
                              void* d_out, int out_size, void* d_ws, size_t ws_size,
                              hipStream_t stream) {
    const float* h    = (const float*)d_in[0];
    const int*   yhat = (const int*)d_in[1];
    const int    N    = in_sizes[1];

    float* out    = (float*)d_out;
    float* grams  = (float*)d_ws;
    int*   counts = (int*)((char*)d_ws + NCLS * 64 * 64 * sizeof(float));

    hipMemsetAsync(d_ws, 0, NCLS * 64 * 64 * sizeof(float) + NCLS * sizeof(int), stream);
    hipMemsetAsync(d_out, 0, out_size * sizeof(float), stream);

    HL_hist<<<128, 256, 0, stream>>>(yhat, counts, N);

    const int ntiles = (N + TILE - 1) / TILE;
    const int nblk   = ntiles < 512 ? ntiles : 512;
    HL_gram<<<nblk, TPB, 0, stream>>>(h, yhat, grams, N, ntiles);

    HL_chol<<<NCLS, 64, 0, stream>>>(grams, counts, out);
}

// Round 2
// 163.351 us; speedup vs baseline: 1.2397x; 1.2397x over previous
//
#include <hip/hip_runtime.h>
#include <hip/hip_bf16.h>

// ---------- types ----------
typedef __attribute__((ext_vector_type(8))) short  short8;
typedef __attribute__((ext_vector_type(4))) short  short4v;
typedef __attribute__((ext_vector_type(4))) float  f32x4;
typedef __attribute__((ext_vector_type(4))) int    i32x4;

#define NCLS  10
#define TILE  256
#define TPB   1024         // 16 waves: waves 0-9 compute classes, all 16 stage
#define NQ    10           // upper-triangular 16x16 quads of the 64x64 Gram
#define PPB   (NQ * NCLS * 256)   // floats of partial data per block (25600)

// fp32 -> bf16 round-to-nearest-even
static __device__ inline unsigned short f2bf(float x) {
    unsigned u = __builtin_bit_cast(unsigned, x);
    unsigned r = (u + 0x7FFFu + ((u >> 16) & 1u)) >> 16;
    return (unsigned short)r;
}

// swizzled element index into the transposed LDS tile [64][256] bf16
static __device__ inline int lds_elem(int d, int row) {
    return d * 256 + ((((row >> 3) ^ ((d >> 1) & 7))) << 3) + (row & 7);
}

// ---------- kernel 1: masked Grams via MFMA (upper quads only) ----------
// partials: [G][NCLS][NQ][256] f32 (fully overwritten; no memset needed)
__global__ __launch_bounds__(TPB, 4) void HL_gram(
        const float* __restrict__ h, const int* __restrict__ yhat,
        float* __restrict__ partials, int* __restrict__ counts,
        int N, int ntiles, int G) {
    __shared__ __align__(16) unsigned short hs[2][64 * 256];
    __shared__ __align__(16) int ysh[2][TILE];

    const int tid  = threadIdx.x;
    const int wid  = tid >> 6;      // wave id; waves 0..9 own class wid
    const int lane = tid & 63;
    const int r4   = tid >> 4;      // 0..63 : rows 4*r4 .. 4*r4+3
    const int d4   = (tid & 15) << 2;

    const int QMB[NQ] = {0,0,0,0,1,1,1,2,2,3};
    const int QNB[NQ] = {0,1,2,3,1,2,3,2,3,3};

    f32x4 acc[NQ];
#pragma unroll
    for (int q = 0; q < NQ; ++q) acc[q] = (f32x4){0.f, 0.f, 0.f, 0.f};
    int cnt = 0;

    f32x4 v[4];
    int   yv = -1;

    // ---- prologue: load first tile into regs ----
    {
        const long base = (long)blockIdx.x * TILE;
#pragma unroll
        for (int j = 0; j < 4; ++j) {
            long g = base + 4L * r4 + j;
            if (g < N) v[j] = *reinterpret_cast<const f32x4*>(h + g * 64 + d4);
            else       v[j] = (f32x4){0.f, 0.f, 0.f, 0.f};
        }
        if (tid < TILE) { long g = base + tid; yv = (g < N) ? yhat[g] : -1; }
    }

    int cur = 0;
    for (int t = blockIdx.x; t < ntiles; t += G) {
        // ---- convert regs -> bf16, write swizzled LDS[cur] ----
#pragma unroll
        for (int q = 0; q < 4; ++q) {
            const int d = d4 + q;
            short4v pk;
            pk[0] = (short)f2bf(v[0][q]);
            pk[1] = (short)f2bf(v[1][q]);
            pk[2] = (short)f2bf(v[2][q]);
            pk[3] = (short)f2bf(v[3][q]);
            *reinterpret_cast<short4v*>(&hs[cur][lds_elem(d, r4 << 2)]) = pk;
        }
        if (tid < TILE) ysh[cur][tid] = yv;

        // ---- prefetch next tile into regs (hidden under MFMA phase) ----
        if (t + G < ntiles) {
            const long base = (long)(t + G) * TILE;
#pragma unroll
            for (int j = 0; j < 4; ++j) {
                long g = base + 4L * r4 + j;
                if (g < N) v[j] = *reinterpret_cast<const f32x4*>(h + g * 64 + d4);
                else       v[j] = (f32x4){0.f, 0.f, 0.f, 0.f};
            }
            if (tid < TILE) { long g = base + tid; yv = (g < N) ? yhat[g] : -1; }
        }

        __syncthreads();   // LDS[cur] ready; also separates from prior readers

        // ---- compute: wave wid accumulates class-wid upper Gram quads ----
        if (wid < NCLS) {
#pragma unroll
            for (int ks = 0; ks < TILE / 32; ++ks) {
                const int krow = ks * 32 + ((lane >> 4) << 3);
                const i32x4 ya = *reinterpret_cast<const i32x4*>(&ysh[cur][krow]);
                const i32x4 yb = *reinterpret_cast<const i32x4*>(&ysh[cur][krow + 4]);
                short8 mask;
                mask[0] = (ya[0] == wid) ? (short)-1 : (short)0;
                mask[1] = (ya[1] == wid) ? (short)-1 : (short)0;
                mask[2] = (ya[2] == wid) ? (short)-1 : (short)0;
                mask[3] = (ya[3] == wid) ? (short)-1 : (short)0;
                mask[4] = (yb[0] == wid) ? (short)-1 : (short)0;
                mask[5] = (yb[1] == wid) ? (short)-1 : (short)0;
                mask[6] = (yb[2] == wid) ? (short)-1 : (short)0;
                mask[7] = (yb[3] == wid) ? (short)-1 : (short)0;
                cnt += (ya[0] == wid) + (ya[1] == wid) + (ya[2] == wid) + (ya[3] == wid)
                     + (yb[0] == wid) + (yb[1] == wid) + (yb[2] == wid) + (yb[3] == wid);

                short8 raw[4], am[4];
#pragma unroll
                for (int nb = 0; nb < 4; ++nb) {
                    const int d = nb * 16 + (lane & 15);
                    raw[nb] = *reinterpret_cast<const short8*>(&hs[cur][lds_elem(d, krow)]);
                    am[nb]  = raw[nb] & mask;
                }
#pragma unroll
                for (int q = 0; q < NQ; ++q)
                    acc[q] = __builtin_amdgcn_mfma_f32_16x16x32_bf16(
                        am[QMB[q]], raw[QNB[q]], acc[q], 0, 0, 0);
            }
        }
        __syncthreads();   // all readers of LDS[cur] done before it is rewritten
        cur ^= 1;
    }

    // ---- epilogue: stream packed partials; per-class counts ----
    if (wid < NCLS) {
        float* pb = partials + (size_t)blockIdx.x * PPB + (size_t)wid * NQ * 256;
#pragma unroll
        for (int q = 0; q < NQ; ++q)
            *reinterpret_cast<f32x4*>(pb + q * 256 + (lane << 2)) = acc[q];
        const int tot = __shfl(cnt, 0) + __shfl(cnt, 16) + __shfl(cnt, 32) + __shfl(cnt, 48);
        if (lane == 0) atomicAdd(&counts[wid], tot);
    }
}

// ---------- kernel 2: reduce partials over blocks into grams (upper quads) ----------
__global__ void HL_reduce(const float* __restrict__ partials, float* __restrict__ grams,
                          int G, int CS, int nthreads) {
    const int idx = blockIdx.x * blockDim.x + threadIdx.x;
    if (idx >= nthreads) return;
    const int chunk = idx / (NCLS * NQ * 64);
    const int r     = idx % (NCLS * NQ * 64);
    const int cq    = r >> 6;          // c*NQ + q
    const int lane  = r & 63;

    const int b0 = chunk * CS;
    int b1 = b0 + CS; if (b1 > G) b1 = G;

    f32x4 s = (f32x4){0.f, 0.f, 0.f, 0.f};
    for (int b = b0; b < b1; ++b)
        s += *reinterpret_cast<const f32x4*>(partials + (size_t)b * PPB + cq * 256 + (lane << 2));

    const int QMB[NQ] = {0,0,0,0,1,1,1,2,2,3};
    const int QNB[NQ] = {0,1,2,3,1,2,3,2,3,3};
    const int c  = cq / NQ;
    const int q  = cq % NQ;
    const int row0 = QMB[q] * 16 + ((lane >> 4) << 2);
    const int col  = QNB[q] * 16 + (lane & 15);
    float* g = grams + c * 4096;
#pragma unroll
    for (int rr = 0; rr < 4; ++rr)
        atomicAdd(&g[(row0 + rr) * 64 + col], s[rr]);
}

// ---------- kernel 3: M = 0.5*G/count + I; loss += 0.5*logdet via Cholesky ----------
__global__ void HL_chol(const float* __restrict__ grams, const int* __restrict__ counts,
                        float* __restrict__ out) {
    __shared__ float M[64][65];
    __shared__ float lcol[64];
    const int cls = blockIdx.x;
    const int i   = threadIdx.x; // 0..63, one wave

    const float inv = 0.5f / (float)counts[cls];
    const float* g  = grams + cls * 4096;
    for (int c = 0; c < 64; ++c) {
        // only upper quads (mb<=nb) are populated; use symmetry for the rest
        const float v = ((i >> 4) <= (c >> 4)) ? g[i * 64 + c] : g[c * 64 + i];
        M[i][c] = v * inv + (i == c ? 1.0f : 0.0f);
    }

    float slog = 0.0f;
    for (int j = 0; j < 64; ++j) {
        __syncthreads();
        const float pivotsq = M[j][j];
        const float pivot   = sqrtf(pivotsq);
        lcol[i] = M[i][j] / pivot;
        if (i == 0) slog += logf(pivotsq);
        __syncthreads();
        if (i > j) {
            const float lij = lcol[i];
            for (int c = j + 1; c <= i; ++c) M[i][c] -= lij * lcol[c];
        }
    }
    if (i == 0) atomicAdd(out, 0.5f * slog);
}

// ---------- launcher ----------
extern "C" void kernel_launch(void* const* d_in, const int* in_sizes, int n_in,
                              void* d_out, int out_size, void* d_ws, size_t ws_size,
                              hipStream_t stream) {
    const float* h    = (const float*)d_in[0];
    const int*   yhat = (const int*)d_in[1];
    const int    N    = in_sizes[1];

    float* out = (float*)d_out;

    // ws layout: [grams 40960 f32][counts 10 int, padded][partials G*PPB f32]
    const size_t grams_off    = 0;
    const size_t counts_off   = 40960 * sizeof(float);          // 163840
    const size_t partials_off = counts_off + 256;               // 164096, 16B aligned
    float* grams    = (float*)((char*)d_ws + grams_off);
    int*   counts   = (int*)((char*)d_ws + counts_off);
    float* partials = (float*)((char*)d_ws + partials_off);

    const int ntiles = (N + TILE - 1) / TILE;
    int G = 256;
    if (ws_size < partials_off + (size_t)G * PPB * sizeof(float)) {
        size_t avail = (ws_size > partials_off) ? (ws_size - partials_off) : 0;
        G = (int)(avail / ((size_t)PPB * sizeof(float)));
        if (G < 1) G = 1;
    }
    if (G > ntiles) G = ntiles;

    hipMemsetAsync(d_ws, 0, partials_off, stream);              // grams + counts
    hipMemsetAsync(d_out, 0, out_size * sizeof(float), stream);

    HL_gram<<<G, TPB, 0, stream>>>(h, yhat, partials, counts, N, ntiles, G);

    int NCH = 16;
    int CS  = (G + NCH - 1) / NCH;
    if (CS < 1) CS = 1;
    NCH = (G + CS - 1) / CS;
    const int nthreads = NCLS * NQ * 64 * NCH;
    HL_reduce<<<(nthreads + 255) / 256, 256, 0, stream>>>(partials, grams, G, CS, nthreads);

    HL_chol<<<NCLS, 64, 0, stream>>>(grams, counts, out);
}

// Round 3
// 137.960 us; speedup vs baseline: 1.4678x; 1.1840x over previous
//
#include <hip/hip_runtime.h>
#include <hip/hip_bf16.h>

// ---------- types ----------
typedef __attribute__((ext_vector_type(8))) short  short8;
typedef __attribute__((ext_vector_type(4))) short  short4v;
typedef __attribute__((ext_vector_type(4))) float  f32x4;

#define NCLS 10
#define TILE 256
#define TPB  1024          // 16 waves
#define NQ   10            // upper-triangular 16x16 quads of 64x64 Gram
#define PPB  (NCLS * NQ * 256)   // floats per block of partials (25600)

// fp32 -> bf16 round-to-nearest-even
static __device__ inline unsigned short f2bf(float x) {
    unsigned u = __builtin_bit_cast(unsigned, x);
    unsigned r = (u + 0x7FFFu + ((u >> 16) & 1u)) >> 16;
    return (unsigned short)r;
}

// ---------- kernel 1: per-class counts ----------
__global__ void HL_hist(const int* __restrict__ yhat, int* __restrict__ counts, int N) {
    __shared__ int lh[NCLS];
    if (threadIdx.x < NCLS) lh[threadIdx.x] = 0;
    __syncthreads();
    long stride = (long)gridDim.x * blockDim.x;
    for (long i = (long)blockIdx.x * blockDim.x + threadIdx.x; i < N; i += stride)
        atomicAdd(&lh[yhat[i]], 1);
    __syncthreads();
    if (threadIdx.x < NCLS) atomicAdd(&counts[threadIdx.x], lh[threadIdx.x]);
}

// ---------- staging: global -> registers ----------
template<bool GUARD>
static __device__ __forceinline__ void stage_load(
        const float* __restrict__ h, const int* __restrict__ yhat,
        long t, int N, int r4, int d4, int tid, f32x4 (&v)[4], int& yv) {
    const float* p = h + (size_t)t * (TILE * 64) + (size_t)r4 * 256 + d4;
#pragma unroll
    for (int j = 0; j < 4; ++j) {
        if (!GUARD) {
            v[j] = *reinterpret_cast<const f32x4*>(p + j * 64);
        } else {
            long g = t * TILE + 4L * r4 + j;
            if (g < N) v[j] = *reinterpret_cast<const f32x4*>(p + j * 64);
            else       v[j] = (f32x4){0.f, 0.f, 0.f, 0.f};
        }
    }
    if (tid < TILE) {
        long g = t * TILE + tid;
        yv = (!GUARD || g < N) ? yhat[g] : -1;
    }
}

// ---------- registers -> LDS (bf16 transpose + swizzle) + class masks ----------
static __device__ __forceinline__ void convert_write(
        const f32x4 (&v)[4], int yv, char* hsbuf, unsigned short* mkbuf,
        const int (&woff)[4], int tid) {
#pragma unroll
    for (int q = 0; q < 4; ++q) {
        short4v pk;
        pk[0] = (short)f2bf(v[0][q]);
        pk[1] = (short)f2bf(v[1][q]);
        pk[2] = (short)f2bf(v[2][q]);
        pk[3] = (short)f2bf(v[3][q]);
        *reinterpret_cast<short4v*>(hsbuf + woff[q]) = pk;
    }
    if (tid < TILE) {
#pragma unroll
        for (int c = 0; c < NCLS; ++c)
            mkbuf[c * 256 + tid] = (yv == c) ? (unsigned short)0xFFFFu : (unsigned short)0u;
    }
}

// ---------- compute: NS k-slices for one class, both MFMA operands masked ----------
template<int NS>
static __device__ __forceinline__ void compute_range(
        const char* hsb, const unsigned short* mkbuf,
        int cls, int ks0, int hi, int col, f32x4 (&acc)[NQ]) {
    const int tb = col << 9;        // col*512 bytes
    const int b  = col >> 1;        // xor term
#pragma unroll
    for (int s = 0; s < NS; ++s) {
        const int ks = ks0 + s;
        const short8 m = *reinterpret_cast<const short8*>(&mkbuf[cls * 256 + ks * 32 + hi * 8]);
        const int x = (((ks * 4 + hi) ^ b) << 4) + tb;
        short8 am[4];
#pragma unroll
        for (int nb = 0; nb < 4; ++nb) {
            short8 r = *reinterpret_cast<const short8*>(hsb + x + nb * 8192);
            am[nb] = r & m;
        }
        acc[0] = __builtin_amdgcn_mfma_f32_16x16x32_bf16(am[0], am[0], acc[0], 0, 0, 0);
        acc[1] = __builtin_amdgcn_mfma_f32_16x16x32_bf16(am[0], am[1], acc[1], 0, 0, 0);
        acc[2] = __builtin_amdgcn_mfma_f32_16x16x32_bf16(am[0], am[2], acc[2], 0, 0, 0);
        acc[3] = __builtin_amdgcn_mfma_f32_16x16x32_bf16(am[0], am[3], acc[3], 0, 0, 0);
        acc[4] = __builtin_amdgcn_mfma_f32_16x16x32_bf16(am[1], am[1], acc[4], 0, 0, 0);
        acc[5] = __builtin_amdgcn_mfma_f32_16x16x32_bf16(am[1], am[2], acc[5], 0, 0, 0);
        acc[6] = __builtin_amdgcn_mfma_f32_16x16x32_bf16(am[1], am[3], acc[6], 0, 0, 0);
        acc[7] = __builtin_amdgcn_mfma_f32_16x16x32_bf16(am[2], am[2], acc[7], 0, 0, 0);
        acc[8] = __builtin_amdgcn_mfma_f32_16x16x32_bf16(am[2], am[3], acc[8], 0, 0, 0);
        acc[9] = __builtin_amdgcn_mfma_f32_16x16x32_bf16(am[3], am[3], acc[9], 0, 0, 0);
    }
}

// ---------- kernel 2: masked Grams via MFMA ----------
__global__ __launch_bounds__(TPB) void HL_gram(
        const float* __restrict__ h, const int* __restrict__ yhat,
        float* __restrict__ partials, int N, int ntiles, int nfull, int G) {
    __shared__ __align__(16) unsigned short hs[2][16384];        // 64 KB
    __shared__ __align__(16) unsigned short mk[2][NCLS * 256];   // 10 KB

    const int tid  = threadIdx.x;
    const int wid  = tid >> 6;
    const int lane = tid & 63;
    const int hi   = lane >> 4;
    const int col  = lane & 15;
    const int r4   = tid >> 4;
    const int d4   = (tid & 15) << 2;

    // wave roles: classes 0-5 split across (w, w+10); 6-9 full range
    int cls, ks0; bool fullr;
    if      (wid < 6)  { cls = wid;      ks0 = 0; fullr = false; }
    else if (wid < 10) { cls = wid;      ks0 = 0; fullr = true;  }
    else               { cls = wid - 10; ks0 = 4; fullr = false; }

    // precomputed swizzled write byte-offsets (tile-invariant)
    int woff[4];
#pragma unroll
    for (int q = 0; q < 4; ++q) {
        const int d   = d4 + q;
        const int row = r4 << 2;
        const int e   = d * 256 + ((((row >> 3) ^ ((d >> 1) & 7))) << 3) + (row & 7);
        woff[q] = e << 1;
    }

    f32x4 acc[NQ];
#pragma unroll
    for (int q = 0; q < NQ; ++q) acc[q] = (f32x4){0.f, 0.f, 0.f, 0.f};

    f32x4 vA[4], vB[4];
    int yA = -1, yB = -1;

    const int bid = blockIdx.x;
    const int K   = (ntiles - bid + G - 1) / G;   // tiles for this block (>=1)

    {   // prologue: tiles k=0 (and k=1) into regs
        long t0 = bid;
        if (t0 < nfull) stage_load<false>(h, yhat, t0, N, r4, d4, tid, vA, yA);
        else            stage_load<true >(h, yhat, t0, N, r4, d4, tid, vA, yA);
        if (K > 1) {
            long t1 = bid + (long)G;
            if (t1 < nfull) stage_load<false>(h, yhat, t1, N, r4, d4, tid, vB, yB);
            else            stage_load<true >(h, yhat, t1, N, r4, d4, tid, vB, yB);
        }
    }

    int cur = 0;
    for (int k = 0; k < K; k += 2) {
        // ---------- A half ----------
        convert_write(vA, yA, (char*)&hs[cur][0], &mk[cur][0], woff, tid);
        if (k + 2 < K) {
            long t = bid + (long)(k + 2) * G;
            if (t < nfull) stage_load<false>(h, yhat, t, N, r4, d4, tid, vA, yA);
            else           stage_load<true >(h, yhat, t, N, r4, d4, tid, vA, yA);
        }
        __syncthreads();
        if (fullr) compute_range<8>((const char*)&hs[cur][0], &mk[cur][0], cls, 0,   hi, col, acc);
        else       compute_range<4>((const char*)&hs[cur][0], &mk[cur][0], cls, ks0, hi, col, acc);
        __syncthreads();
        cur ^= 1;

        // ---------- B half ----------
        if (k + 1 < K) {
            convert_write(vB, yB, (char*)&hs[cur][0], &mk[cur][0], woff, tid);
            if (k + 3 < K) {
                long t = bid + (long)(k + 3) * G;
                if (t < nfull) stage_load<false>(h, yhat, t, N, r4, d4, tid, vB, yB);
                else           stage_load<true >(h, yhat, t, N, r4, d4, tid, vB, yB);
            }
            __syncthreads();
            if (fullr) compute_range<8>((const char*)&hs[cur][0], &mk[cur][0], cls, 0,   hi, col, acc);
            else       compute_range<4>((const char*)&hs[cur][0], &mk[cur][0], cls, ks0, hi, col, acc);
            __syncthreads();
            cur ^= 1;
        }
    }

    // ---------- merge split-class halves (waves 10-15 -> waves 0-5) ----------
    float* xch = (float*)&hs[0][0];   // hs dead now; 12 KB per round
#pragma unroll
    for (int qq = 0; qq < NQ; qq += 2) {
        __syncthreads();
        if (wid >= 10) {
            float* dst = xch + (wid - 10) * 512;
            *reinterpret_cast<f32x4*>(dst + (lane << 2))       = acc[qq];
            *reinterpret_cast<f32x4*>(dst + 256 + (lane << 2)) = acc[qq + 1];
        }
        __syncthreads();
        if (wid < 6) {
            const float* src = xch + wid * 512;
            acc[qq]     += *reinterpret_cast<const f32x4*>(src + (lane << 2));
            acc[qq + 1] += *reinterpret_cast<const f32x4*>(src + 256 + (lane << 2));
        }
    }

    // ---------- stream partials (waves 0-9) ----------
    if (wid < NCLS) {
        float* pb = partials + (size_t)bid * PPB + (size_t)wid * (NQ * 256);
#pragma unroll
        for (int q = 0; q < NQ; ++q)
            *reinterpret_cast<f32x4*>(pb + q * 256 + (lane << 2)) = acc[q];
    }
}

// ---------- kernel 3: reduce partials over blocks (atomic-free) ----------
__global__ void HL_reduce(const float* __restrict__ partials, float* __restrict__ grams, int G) {
    const int idx = blockIdx.x * blockDim.x + threadIdx.x;
    if (idx >= NCLS * NQ * 64) return;
    const int cq   = idx >> 6;
    const int lane = idx & 63;

    f32x4 s = (f32x4){0.f, 0.f, 0.f, 0.f};
    const float* p = partials + cq * 256 + (lane << 2);
#pragma unroll 8
    for (int b = 0; b < G; ++b)
        s += *reinterpret_cast<const f32x4*>(p + (size_t)b * PPB);

    const int QMB[NQ] = {0,0,0,0,1,1,1,2,2,3};
    const int QNB[NQ] = {0,1,2,3,1,2,3,2,3,3};
    const int c    = cq / NQ;
    const int q    = cq % NQ;
    const int row0 = QMB[q] * 16 + ((lane >> 4) << 2);
    const int colo = QNB[q] * 16 + (lane & 15);
    float* g = grams + c * 4096;
#pragma unroll
    for (int rr = 0; rr < 4; ++rr)
        g[(row0 + rr) * 64 + colo] = s[rr];
}

// ---------- kernel 4: M = 0.5*G/count + I; loss += 0.5*logdet (Cholesky) ----------
__global__ __launch_bounds__(1024) void HL_chol(
        const float* __restrict__ grams, const int* __restrict__ counts,
        float* __restrict__ out) {
    __shared__ float M[64][65];
    __shared__ float lcol[64];
    __shared__ float plog[64];
    const int tid = threadIdx.x;
    const int i   = tid & 63;
    const int g   = tid >> 6;       // 0..15
    const int cls = blockIdx.x;

    const float inv = 0.5f / (float)counts[cls];
    const float* gr = grams + cls * 4096;
#pragma unroll
    for (int cc = 0; cc < 4; ++cc) {
        const int c = g * 4 + cc;
        const float v = ((i >> 4) <= (c >> 4)) ? gr[i * 64 + c] : gr[c * 64 + i];
        M[i][c] = v * inv + (i == c ? 1.0f : 0.0f);
    }
    __syncthreads();

    for (int j = 0; j < 64; ++j) {
        const float piv = M[j][j];
        if (tid == 0) plog[j] = piv;
        const float is = rsqrtf(piv);
        if (g == 0) lcol[i] = M[i][j] * is;
        __syncthreads();
        if (i > j) {
            const float lij = lcol[i];
            for (int c = j + 1 + g; c <= i; c += 16)
                M[i][c] -= lij * lcol[c];
        }
        __syncthreads();
    }

    if (tid < 64) {
        float l = logf(plog[tid]);
        l += __shfl_down(l, 32); l += __shfl_down(l, 16); l += __shfl_down(l, 8);
        l += __shfl_down(l, 4);  l += __shfl_down(l, 2);  l += __shfl_down(l, 1);
        if (tid == 0) atomicAdd(out, 0.5f * l);
    }
}

// ---------- launcher ----------
extern "C" void kernel_launch(void* const* d_in, const int* in_sizes, int n_in,
                              void* d_out, int out_size, void* d_ws, size_t ws_size,
                              hipStream_t stream) {
    const float* h    = (const float*)d_in[0];
    const int*   yhat = (const int*)d_in[1];
    const int    N    = in_sizes[1];

    float* out = (float*)d_out;

    // ws layout: [grams 40960 f32][counts 10 int pad 256B][partials G*PPB f32]
    const size_t counts_off   = 40960 * sizeof(float);   // 163840
    const size_t partials_off = counts_off + 256;        // 164096
    float* grams    = (float*)d_ws;
    int*   counts   = (int*)((char*)d_ws + counts_off);
    float* partials = (float*)((char*)d_ws + partials_off);

    const int ntiles = (N + TILE - 1) / TILE;
    const int nfull  = N / TILE;
    int G = 256;
    if (ws_size < partials_off + (size_t)G * PPB * sizeof(float)) {
        size_t avail = (ws_size > partials_off) ? (ws_size - partials_off) : 0;
        G = (int)(avail / ((size_t)PPB * sizeof(float)));
        if (G < 1) G = 1;
    }
    if (G > ntiles) G = ntiles;

    hipMemsetAsync((char*)d_ws + counts_off, 0, 256, stream);
    hipMemsetAsync(d_out, 0, out_size * sizeof(float), stream);

    HL_hist<<<256, 256, 0, stream>>>(yhat, counts, N);
    HL_gram<<<G, TPB, 0, stream>>>(h, yhat, partials, N, ntiles, nfull, G);
    HL_reduce<<<(NCLS * NQ * 64 + 255) / 256, 256, 0, stream>>>(partials, grams, G);
    HL_chol<<<NCLS, 1024, 0, stream>>>(grams, counts, out);
}

// Round 4
// 108.467 us; speedup vs baseline: 1.8669x; 1.2719x over previous
//
#include <hip/hip_runtime.h>
#include <hip/hip_bf16.h>

// ---------- types ----------
typedef __attribute__((ext_vector_type(8))) short  short8;
typedef __attribute__((ext_vector_type(4))) short  short4v;
typedef __attribute__((ext_vector_type(4))) float  f32x4;

#define NCLS 10
#define TILE 256
#define TPB  1024          // 16 waves
#define NQ   10            // upper-triangular 16x16 quads of 64x64 Gram
#define PPB  (NCLS * NQ * 256)   // floats per block of partials (25600)
#define CH   8             // reduction chunks

// fp32 -> bf16 round-to-nearest-even
static __device__ inline unsigned short f2bf(float x) {
    unsigned u = __builtin_bit_cast(unsigned, x);
    unsigned r = (u + 0x7FFFu + ((u >> 16) & 1u)) >> 16;
    return (unsigned short)r;
}

// ---------- staging: global -> registers ----------
template<bool GUARD>
static __device__ __forceinline__ void stage_load(
        const float* __restrict__ h, const int* __restrict__ yhat,
        long t, int N, int r4, int d4, int tid, f32x4 (&v)[4], int& yv) {
    const float* p = h + (size_t)t * (TILE * 64) + (size_t)r4 * 256 + d4;
#pragma unroll
    for (int j = 0; j < 4; ++j) {
        if (!GUARD) {
            v[j] = *reinterpret_cast<const f32x4*>(p + j * 64);
        } else {
            long g = t * TILE + 4L * r4 + j;
            if (g < N) v[j] = *reinterpret_cast<const f32x4*>(p + j * 64);
            else       v[j] = (f32x4){0.f, 0.f, 0.f, 0.f};
        }
    }
    if (tid < TILE) {
        long g = t * TILE + tid;
        yv = (!GUARD || g < N) ? yhat[g] : -1;
    }
}

// ---------- registers -> LDS (bf16 transpose + swizzle) + masks + counts ----------
static __device__ __forceinline__ void convert_write(
        const f32x4 (&v)[4], int yv, char* hsbuf, unsigned short* mkbuf,
        int* cntlds, const int (&woff)[4], int tid, int lane) {
#pragma unroll
    for (int q = 0; q < 4; ++q) {
        short4v pk;
        pk[0] = (short)f2bf(v[0][q]);
        pk[1] = (short)f2bf(v[1][q]);
        pk[2] = (short)f2bf(v[2][q]);
        pk[3] = (short)f2bf(v[3][q]);
        *reinterpret_cast<short4v*>(hsbuf + woff[q]) = pk;
    }
    if (tid < TILE) {   // waves 0-3 exactly, no intra-wave divergence
#pragma unroll
        for (int c = 0; c < NCLS; ++c) {
            mkbuf[c * 256 + tid] = (yv == c) ? (unsigned short)0xFFFFu : (unsigned short)0u;
            unsigned long long b = __ballot(yv == c);
            if (lane == 0) atomicAdd(&cntlds[c], __popcll(b));
        }
    }
}

// ---------- compute: NS k-slices for one class, both MFMA operands masked ----------
template<int NS>
static __device__ __forceinline__ void compute_range(
        const char* hsb, const unsigned short* mkbuf,
        int cls, int ks0, int hi, int col, f32x4 (&acc)[NQ]) {
    const int tb = col << 9;        // col*512 bytes
    const int b  = col >> 1;        // xor term
#pragma unroll
    for (int s = 0; s < NS; ++s) {
        const int ks = ks0 + s;
        const short8 m = *reinterpret_cast<const short8*>(&mkbuf[cls * 256 + ks * 32 + hi * 8]);
        const int x = (((ks * 4 + hi) ^ b) << 4) + tb;
        short8 am[4];
#pragma unroll
        for (int nb = 0; nb < 4; ++nb) {
            short8 r = *reinterpret_cast<const short8*>(hsb + x + nb * 8192);
            am[nb] = r & m;
        }
        acc[0] = __builtin_amdgcn_mfma_f32_16x16x32_bf16(am[0], am[0], acc[0], 0, 0, 0);
        acc[1] = __builtin_amdgcn_mfma_f32_16x16x32_bf16(am[0], am[1], acc[1], 0, 0, 0);
        acc[2] = __builtin_amdgcn_mfma_f32_16x16x32_bf16(am[0], am[2], acc[2], 0, 0, 0);
        acc[3] = __builtin_amdgcn_mfma_f32_16x16x32_bf16(am[0], am[3], acc[3], 0, 0, 0);
        acc[4] = __builtin_amdgcn_mfma_f32_16x16x32_bf16(am[1], am[1], acc[4], 0, 0, 0);
        acc[5] = __builtin_amdgcn_mfma_f32_16x16x32_bf16(am[1], am[2], acc[5], 0, 0, 0);
        acc[6] = __builtin_amdgcn_mfma_f32_16x16x32_bf16(am[1], am[3], acc[6], 0, 0, 0);
        acc[7] = __builtin_amdgcn_mfma_f32_16x16x32_bf16(am[2], am[2], acc[7], 0, 0, 0);
        acc[8] = __builtin_amdgcn_mfma_f32_16x16x32_bf16(am[2], am[3], acc[8], 0, 0, 0);
        acc[9] = __builtin_amdgcn_mfma_f32_16x16x32_bf16(am[3], am[3], acc[9], 0, 0, 0);
    }
}

// ---------- kernel 1: masked Grams via MFMA ----------
// partials: [G][NCLS][NQ][256] f32; cntp: [G][16] int. Both fully overwritten.
__global__ __launch_bounds__(TPB, 4) void HL_gram(
        const float* __restrict__ h, const int* __restrict__ yhat,
        float* __restrict__ partials, int* __restrict__ cntp,
        int N, int ntiles, int nfull, int G) {
    __shared__ __align__(16) unsigned short hs[2][16384];        // 64 KB
    __shared__ __align__(16) unsigned short mk[2][NCLS * 256];   // 10 KB
    __shared__ int cntlds[16];

    const int tid  = threadIdx.x;
    const int wid  = tid >> 6;
    const int lane = tid & 63;
    const int hi   = lane >> 4;
    const int col  = lane & 15;
    const int r4   = tid >> 4;
    const int d4   = (tid & 15) << 2;

    if (tid < 16) cntlds[tid] = 0;
    __syncthreads();

    // wave roles: classes 0-5 split across (w, w+10); 6-9 full range
    int cls, ks0; bool fullr;
    if      (wid < 6)  { cls = wid;      ks0 = 0; fullr = false; }
    else if (wid < 10) { cls = wid;      ks0 = 0; fullr = true;  }
    else               { cls = wid - 10; ks0 = 4; fullr = false; }

    // precomputed swizzled write byte-offsets (tile-invariant)
    int woff[4];
#pragma unroll
    for (int q = 0; q < 4; ++q) {
        const int d   = d4 + q;
        const int row = r4 << 2;
        const int e   = d * 256 + ((((row >> 3) ^ ((d >> 1) & 7))) << 3) + (row & 7);
        woff[q] = e << 1;
    }

    f32x4 acc[NQ];
#pragma unroll
    for (int q = 0; q < NQ; ++q) acc[q] = (f32x4){0.f, 0.f, 0.f, 0.f};

    f32x4 vA[4], vB[4];
    int yA = -1, yB = -1;

    const int bid = blockIdx.x;
    const int K   = (ntiles - bid + G - 1) / G;   // tiles for this block (>=1)

    {   // prologue: tiles k=0 (and k=1) into regs
        long t0 = bid;
        if (t0 < nfull) stage_load<false>(h, yhat, t0, N, r4, d4, tid, vA, yA);
        else            stage_load<true >(h, yhat, t0, N, r4, d4, tid, vA, yA);
        if (K > 1) {
            long t1 = bid + (long)G;
            if (t1 < nfull) stage_load<false>(h, yhat, t1, N, r4, d4, tid, vB, yB);
            else            stage_load<true >(h, yhat, t1, N, r4, d4, tid, vB, yB);
        }
    }

    int cur = 0;
    for (int k = 0; k < K; k += 2) {
        // ---------- A half ----------
        convert_write(vA, yA, (char*)&hs[cur][0], &mk[cur][0], cntlds, woff, tid, lane);
        if (k + 2 < K) {
            long t = bid + (long)(k + 2) * G;
            if (t < nfull) stage_load<false>(h, yhat, t, N, r4, d4, tid, vA, yA);
            else           stage_load<true >(h, yhat, t, N, r4, d4, tid, vA, yA);
        }
        __syncthreads();
        if (fullr) compute_range<8>((const char*)&hs[cur][0], &mk[cur][0], cls, 0,   hi, col, acc);
        else       compute_range<4>((const char*)&hs[cur][0], &mk[cur][0], cls, ks0, hi, col, acc);
        __syncthreads();
        cur ^= 1;

        // ---------- B half ----------
        if (k + 1 < K) {
            convert_write(vB, yB, (char*)&hs[cur][0], &mk[cur][0], cntlds, woff, tid, lane);
            if (k + 3 < K) {
                long t = bid + (long)(k + 3) * G;
                if (t < nfull) stage_load<false>(h, yhat, t, N, r4, d4, tid, vB, yB);
                else           stage_load<true >(h, yhat, t, N, r4, d4, tid, vB, yB);
            }
            __syncthreads();
            if (fullr) compute_range<8>((const char*)&hs[cur][0], &mk[cur][0], cls, 0,   hi, col, acc);
            else       compute_range<4>((const char*)&hs[cur][0], &mk[cur][0], cls, ks0, hi, col, acc);
            __syncthreads();
            cur ^= 1;
        }
    }

    // ---------- merge split-class halves (waves 10-15 -> waves 0-5) ----------
    float* xch = (float*)&hs[0][0];   // hs dead now
#pragma unroll
    for (int qq = 0; qq < NQ; qq += 2) {
        __syncthreads();
        if (wid >= 10) {
            float* dst = xch + (wid - 10) * 512;
            *reinterpret_cast<f32x4*>(dst + (lane << 2))       = acc[qq];
            *reinterpret_cast<f32x4*>(dst + 256 + (lane << 2)) = acc[qq + 1];
        }
        __syncthreads();
        if (wid < 6) {
            const float* src = xch + wid * 512;
            acc[qq]     += *reinterpret_cast<const f32x4*>(src + (lane << 2));
            acc[qq + 1] += *reinterpret_cast<const f32x4*>(src + 256 + (lane << 2));
        }
    }

    // ---------- stream partials (waves 0-9) + per-block counts ----------
    if (wid < NCLS) {
        float* pb = partials + (size_t)bid * PPB + (size_t)wid * (NQ * 256);
#pragma unroll
        for (int q = 0; q < NQ; ++q)
            *reinterpret_cast<f32x4*>(pb + q * 256 + (lane << 2)) = acc[q];
    }
    if (tid < NCLS) cntp[bid * 16 + tid] = cntlds[tid];
}

// ---------- kernel 2: chunked block-reduction of partials (atomic-free) ----------
// rpart: [CH][NCLS*NQ][256] f32, fully overwritten. Also zeroes out[0].
__global__ void HL_reduce(const float* __restrict__ partials, float* __restrict__ rpart,
                          float* __restrict__ out, int G, int CS) {
    const int idx = blockIdx.x * blockDim.x + threadIdx.x;
    if (blockIdx.x == 0 && threadIdx.x == 0) out[0] = 0.f;
    if (idx >= CH * NCLS * NQ * 64) return;
    const int ch = idx / (NCLS * NQ * 64);
    const int r  = idx % (NCLS * NQ * 64);
    const int cq = r >> 6;
    const int l  = r & 63;

    int b0 = ch * CS;
    int b1 = b0 + CS; if (b1 > G) b1 = G;

    f32x4 s = (f32x4){0.f, 0.f, 0.f, 0.f};
    const float* p = partials + (size_t)cq * 256 + (l << 2);
    for (int b = b0; b < b1; ++b)
        s += *reinterpret_cast<const f32x4*>(p + (size_t)b * PPB);

    *reinterpret_cast<f32x4*>(rpart + ((size_t)ch * (NCLS * NQ) + cq) * 256 + (l << 2)) = s;
}

// ---------- kernel 3: counts + M = 0.5*G/cnt + I; loss += 0.5*logdet ----------
// One wave per class; rows in registers; fully unrolled Cholesky.
__global__ __launch_bounds__(64, 1) void HL_chol(
        const float* __restrict__ rpart, const int* __restrict__ cntp,
        float* __restrict__ out, int G) {
    __shared__ float M[64][68];
    __shared__ float lcol[64];
    const int cls = blockIdx.x;
    const int i   = threadIdx.x;   // lane 0..63

    // ---- class count from per-block partial counts ----
    int c = 0;
    for (int b = i; b < G; b += 64) c += cntp[b * 16 + cls];
#pragma unroll
    for (int off = 32; off > 0; off >>= 1) c += __shfl_xor(c, off);
    const float inv = 0.5f / (float)c;

    // ---- build symmetric M in LDS from chunked quad partials ----
    const int QMB[NQ] = {0,0,0,0,1,1,1,2,2,3};
    const int QNB[NQ] = {0,1,2,3,1,2,3,2,3,3};
    const float* rp = rpart + (size_t)cls * (NQ * 256);
#pragma unroll
    for (int q = 0; q < NQ; ++q) {
        f32x4 s = (f32x4){0.f, 0.f, 0.f, 0.f};
#pragma unroll
        for (int ch = 0; ch < CH; ++ch)
            s += *reinterpret_cast<const f32x4*>(rp + (size_t)ch * (NCLS * NQ * 256) + q * 256 + (i << 2));
        const int row0 = QMB[q] * 16 + ((i >> 4) << 2);
        const int colo = QNB[q] * 16 + (i & 15);
#pragma unroll
        for (int rr = 0; rr < 4; ++rr) {
            M[row0 + rr][colo] = s[rr];
            M[colo][row0 + rr] = s[rr];    // mirror (diag quads: same slot)
        }
    }
    __syncthreads();

    // ---- rows to registers ----
    float row[64];
#pragma unroll
    for (int c2 = 0; c2 < 64; ++c2)
        row[c2] = M[i][c2] * inv + (c2 == i ? 1.0f : 0.0f);

    // ---- Cholesky, fully unrolled; lane i's row[i] ends as its pivot ----
#pragma unroll
    for (int j = 0; j < 64; ++j) {
        const float piv = __shfl(row[j], j);
        const float li  = row[j] * rsqrtf(piv);
        lcol[i] = li;
        __syncthreads();
#pragma unroll
        for (int c2 = j + 1; c2 < 64; ++c2)
            row[c2] -= li * lcol[c2];      // same-address broadcast reads
        __syncthreads();
    }

    // row[i] (own diag, untouched after step i) is this lane's pivot
    float slog = 0.f;
#pragma unroll
    for (int j = 0; j < 64; ++j)
        if (i == j) slog = __logf(row[j]);   // static index; one lane real per j
    slog += __shfl_down(slog, 32); slog += __shfl_down(slog, 16);
    slog += __shfl_down(slog, 8);  slog += __shfl_down(slog, 4);
    slog += __shfl_down(slog, 2);  slog += __shfl_down(slog, 1);
    if (i == 0) atomicAdd(out, 0.5f * slog);
}

// ---------- launcher ----------
extern "C" void kernel_launch(void* const* d_in, const int* in_sizes, int n_in,
                              void* d_out, int out_size, void* d_ws, size_t ws_size,
                              hipStream_t stream) {
    const float* h    = (const float*)d_in[0];
    const int*   yhat = (const int*)d_in[1];
    const int    N    = in_sizes[1];
    float* out = (float*)d_out;

    // ws layout: [rpart CH*100*256 f32][cntp G*16 int][partials G*PPB f32]
    const size_t rpart_off = 0;
    const size_t rpart_sz  = (size_t)CH * NCLS * NQ * 256 * sizeof(float);  // 819200
    const size_t cntp_off  = rpart_sz;

    const int ntiles = (N + TILE - 1) / TILE;
    const int nfull  = N / TILE;
    int G = 256;
    {   // fit G to workspace: need rpart + G*(64 + PPB*4)
        const size_t perG = 64 + (size_t)PPB * sizeof(float);
        if (ws_size > rpart_sz) {
            size_t maxG = (ws_size - rpart_sz) / perG;
            if ((size_t)G > maxG) G = (int)maxG;
        } else G = 1;
        if (G < 1) G = 1;
    }
    if (G > ntiles) G = ntiles;

    const size_t partials_off = cntp_off + (size_t)G * 16 * sizeof(int);
    float* rpart    = (float*)((char*)d_ws + rpart_off);
    int*   cntp     = (int*)((char*)d_ws + cntp_off);
    float* partials = (float*)((char*)d_ws + partials_off);

    HL_gram<<<G, TPB, 0, stream>>>(h, yhat, partials, cntp, N, ntiles, nfull, G);

    int CS = (G + CH - 1) / CH;
    const int rthreads = CH * NCLS * NQ * 64;   // 51200
    HL_reduce<<<(rthreads + 255) / 256, 256, 0, stream>>>(partials, rpart, out, G, CS);

    HL_chol<<<NCLS, 64, 0, stream>>>(rpart, cntp, out, G);
}

// Round 5
// 81.319 us; speedup vs baseline: 2.4902x; 1.3338x over previous
//
#include <hip/hip_runtime.h>
#include <hip/hip_bf16.h>

// ---------- types ----------
typedef __attribute__((ext_vector_type(8))) short  short8;
typedef __attribute__((ext_vector_type(4))) float  f32x4;

#define NCLS 10
#define TILE 128
#define TPB  1024          // 16 waves
#define NQ   10            // upper-triangular 16x16 quads of 64x64 Gram
#define PPB  (NCLS * NQ * 256)   // floats per block of partials (25600)
#define CH   8             // reduction chunks

#define AS1 __attribute__((address_space(1)))
#define AS3 __attribute__((address_space(3)))

// fp32 -> bf16 round-to-nearest-even
static __device__ inline unsigned short f2bf(float x) {
    unsigned u = __builtin_bit_cast(unsigned, x);
    unsigned r = (u + 0x7FFFu + ((u >> 16) & 1u)) >> 16;
    return (unsigned short)r;
}

// ---------- DMA: one fp32 tile (+yhat) directly into LDS, swizzled source ----------
static __device__ __forceinline__ void issue_tile(
        const float* __restrict__ h, const int* __restrict__ yhat,
        float* fsb, int* yb, long t, int wid, int lane) {
    const size_t tb = (size_t)t * (TILE * 64);   // floats
#pragma unroll
    for (int i = 0; i < 2; ++i) {
        const int C   = (wid * 2 + i) * 64 + lane;   // 16B chunk id, 0..2047
        const int row = C >> 4;
        const int qc  = C & 15;
        const float* gp = h + tb + row * 64 + ((qc ^ (row & 3)) << 2);
        __builtin_amdgcn_global_load_lds((const AS1 float*)gp,
                                         (AS3 float*)(fsb + (wid * 2 + i) * 256),
                                         16, 0, 0);
    }
    if (wid == 0 && lane < 32) {   // 128 ints = 32 lanes x 16B
        const int* gy = yhat + (size_t)t * TILE + lane * 4;
        __builtin_amdgcn_global_load_lds((const AS1 int*)gy, (AS3 int*)yb, 16, 0, 0);
    }
}

// ---------- compute: NS k-slices for one class, both MFMA operands masked ----------
template<int NS>
static __device__ __forceinline__ void compute_range(
        const char* hsb, const char* mkb,
        int cls, int ks0, int hi, int col, f32x4 (&acc)[NQ]) {
    const int cb = col << 8;     // col*256 bytes (row stride of [d][128] bf16)
    const int c7 = col & 7;
#pragma unroll
    for (int s = 0; s < NS; ++s) {
        const int ks = ks0 + s;
        const short8 m = *reinterpret_cast<const short8*>(mkb + cls * 256 + ks * 64 + hi * 16);
        const int x = ((ks * 4 + hi) ^ c7) << 4;
        short8 am[4];
#pragma unroll
        for (int nb = 0; nb < 4; ++nb) {
            short8 r = *reinterpret_cast<const short8*>(hsb + nb * 4096 + cb + x);
            am[nb] = r & m;
        }
        acc[0] = __builtin_amdgcn_mfma_f32_16x16x32_bf16(am[0], am[0], acc[0], 0, 0, 0);
        acc[1] = __builtin_amdgcn_mfma_f32_16x16x32_bf16(am[0], am[1], acc[1], 0, 0, 0);
        acc[2] = __builtin_amdgcn_mfma_f32_16x16x32_bf16(am[0], am[2], acc[2], 0, 0, 0);
        acc[3] = __builtin_amdgcn_mfma_f32_16x16x32_bf16(am[0], am[3], acc[3], 0, 0, 0);
        acc[4] = __builtin_amdgcn_mfma_f32_16x16x32_bf16(am[1], am[1], acc[4], 0, 0, 0);
        acc[5] = __builtin_amdgcn_mfma_f32_16x16x32_bf16(am[1], am[2], acc[5], 0, 0, 0);
        acc[6] = __builtin_amdgcn_mfma_f32_16x16x32_bf16(am[1], am[3], acc[6], 0, 0, 0);
        acc[7] = __builtin_amdgcn_mfma_f32_16x16x32_bf16(am[2], am[2], acc[7], 0, 0, 0);
        acc[8] = __builtin_amdgcn_mfma_f32_16x16x32_bf16(am[2], am[3], acc[8], 0, 0, 0);
        acc[9] = __builtin_amdgcn_mfma_f32_16x16x32_bf16(am[3], am[3], acc[9], 0, 0, 0);
    }
}

// ---------- kernel 1: masked Grams via MFMA ----------
// partials: [G][NCLS][NQ][256] f32; cntp: [G][16] int. Both fully overwritten.
__global__ __launch_bounds__(TPB, 4) void HL_gram(
        const float* __restrict__ h, const int* __restrict__ yhat,
        float* __restrict__ partials, int* __restrict__ cntp,
        int N, int ntiles, int G) {
    __shared__ __align__(16) float          fs[2][TILE * 64];     // 64 KB raw fp32
    __shared__ __align__(16) unsigned short hs[2][64 * TILE];     // 32 KB bf16 swz
    __shared__ __align__(16) unsigned short mk[2][NCLS * TILE];   // 5 KB masks
    __shared__ __align__(16) int            ylds[2][TILE];        // 1 KB
    __shared__ int cntlds[16];

    const int tid  = threadIdx.x;
    const int wid  = tid >> 6;
    const int lane = tid & 63;
    const int hi   = lane >> 4;
    const int col  = lane & 15;
    const int r2   = tid >> 4;           // 0..63 -> rows 2r2, 2r2+1
    const int q16  = tid & 15;           // fp32 col-chunk / bf16 col-group

    if (tid < 16) cntlds[tid] = 0;

    // wave roles: classes 0-5 split across (w, w+10); 6-9 full range
    int cls, ks0, ns;
    if      (wid < 6)  { cls = wid;      ks0 = 0; ns = 2; }
    else if (wid < 10) { cls = wid;      ks0 = 0; ns = 4; }
    else               { cls = wid - 10; ks0 = 2; ns = 2; }

    f32x4 acc[NQ];
#pragma unroll
    for (int q = 0; q < NQ; ++q) acc[q] = (f32x4){0.f, 0.f, 0.f, 0.f};

    const int  bid     = blockIdx.x;
    const int  K       = (ntiles - bid + G - 1) / G;
    const bool partial = (N % TILE) != 0;

    // prologue: DMA tile 0 (skip if it's the partial tail)
    if (!(partial && bid == ntiles - 1))
        issue_tile(h, yhat, &fs[0][0], &ylds[0][0], bid, wid, lane);

    int cur = 0;
    for (int k = 0; k < K; ++k) {
        const long t    = bid + (long)k * G;
        const bool tail = partial && (t == (long)(ntiles - 1));

        __syncthreads();   // bar1: DMA(t) drained; prior compute done

        // ---- convert: fp32 -> bf16 transposed+swizzled, + masks + counts ----
        f32x4 v[2];
#pragma unroll
        for (int j = 0; j < 2; ++j) {
            const int row = r2 * 2 + j;
            if (!tail) {
                v[j] = *reinterpret_cast<const f32x4*>(
                    (const char*)&fs[cur][0] + ((row * 256 + (q16 << 4)) ^ ((row & 3) << 4)));
            } else {
                const long g = t * TILE + row;
                if (g < N) v[j] = *reinterpret_cast<const f32x4*>(h + (size_t)g * 64 + (q16 << 2));
                else       v[j] = (f32x4){0.f, 0.f, 0.f, 0.f};
            }
        }
#pragma unroll
        for (int q = 0; q < 4; ++q) {
            const int d = q16 * 4 + q;
            unsigned pk = (unsigned)f2bf(v[0][q]) | ((unsigned)f2bf(v[1][q]) << 16);
            *reinterpret_cast<unsigned*>(
                (char*)&hs[cur][0] + ((d * 256 + r2 * 4) ^ ((d & 7) << 4))) = pk;
        }
        if (tid < TILE) {
            int y;
            if (!tail) y = ylds[cur][tid];
            else { const long g = t * TILE + tid; y = (g < N) ? yhat[g] : -1; }
#pragma unroll
            for (int c = 0; c < NCLS; ++c) {
                mk[cur][c * TILE + tid] = (y == c) ? (unsigned short)0xFFFFu : (unsigned short)0u;
                unsigned long long b = __ballot(y == c);
                if (lane == 0) atomicAdd(&cntlds[c], __popcll(b));
            }
        }

        __syncthreads();   // bar2: bf16 + masks visible

        // ---- issue DMA for next tile (lands during compute + next convert) ----
        if (k + 1 < K) {
            const long tn = bid + (long)(k + 1) * G;
            if (!(partial && tn == (long)(ntiles - 1)))
                issue_tile(h, yhat, &fs[cur ^ 1][0], &ylds[cur ^ 1][0], tn, wid, lane);
        }

        // ---- compute ----
        if (ns == 4) compute_range<4>((const char*)&hs[cur][0], (const char*)&mk[cur][0],
                                      cls, 0,   hi, col, acc);
        else         compute_range<2>((const char*)&hs[cur][0], (const char*)&mk[cur][0],
                                      cls, ks0, hi, col, acc);
        cur ^= 1;
    }

    // ---------- merge split-class halves (waves 10-15 -> waves 0-5) ----------
    float* xch = (float*)&fs[0][0];
#pragma unroll
    for (int qq = 0; qq < NQ; qq += 2) {
        __syncthreads();
        if (wid >= 10) {
            float* dst = xch + (wid - 10) * 512;
            *reinterpret_cast<f32x4*>(dst + (lane << 2))       = acc[qq];
            *reinterpret_cast<f32x4*>(dst + 256 + (lane << 2)) = acc[qq + 1];
        }
        __syncthreads();
        if (wid < 6) {
            const float* src = xch + wid * 512;
            acc[qq]     += *reinterpret_cast<const f32x4*>(src + (lane << 2));
            acc[qq + 1] += *reinterpret_cast<const f32x4*>(src + 256 + (lane << 2));
        }
    }

    // ---------- stream partials (waves 0-9) + per-block counts ----------
    if (wid < NCLS) {
        float* pb = partials + (size_t)bid * PPB + (size_t)wid * (NQ * 256);
#pragma unroll
        for (int q = 0; q < NQ; ++q)
            *reinterpret_cast<f32x4*>(pb + q * 256 + (lane << 2)) = acc[q];
    }
    if (tid < NCLS) cntp[bid * 16 + tid] = cntlds[tid];
}

// ---------- kernel 2: chunked block-reduction of partials (atomic-free) ----------
// rpart: [CH][NCLS*NQ][256] f32, fully overwritten. Also zeroes out[0].
__global__ void HL_reduce(const float* __restrict__ partials, float* __restrict__ rpart,
                          float* __restrict__ out, int G, int CS) {
    const int idx = blockIdx.x * blockDim.x + threadIdx.x;
    if (blockIdx.x == 0 && threadIdx.x == 0) out[0] = 0.f;
    if (idx >= CH * NCLS * NQ * 64) return;
    const int ch = idx / (NCLS * NQ * 64);
    const int r  = idx % (NCLS * NQ * 64);
    const int cq = r >> 6;
    const int l  = r & 63;

    int b0 = ch * CS;
    int b1 = b0 + CS; if (b1 > G) b1 = G;

    f32x4 s = (f32x4){0.f, 0.f, 0.f, 0.f};
    const float* p = partials + (size_t)cq * 256 + (l << 2);
    for (int b = b0; b < b1; ++b)
        s += *reinterpret_cast<const f32x4*>(p + (size_t)b * PPB);

    *reinterpret_cast<f32x4*>(rpart + ((size_t)ch * (NCLS * NQ) + cq) * 256 + (l << 2)) = s;
}

// ---------- kernel 3: counts + M = 0.5*G/cnt + I; loss += 0.5*logdet ----------
__global__ __launch_bounds__(64, 1) void HL_chol(
        const float* __restrict__ rpart, const int* __restrict__ cntp,
        float* __restrict__ out, int G) {
    __shared__ float M[64][68];
    __shared__ float lcol[64];
    const int cls = blockIdx.x;
    const int i   = threadIdx.x;   // lane 0..63

    int c = 0;
    for (int b = i; b < G; b += 64) c += cntp[b * 16 + cls];
#pragma unroll
    for (int off = 32; off > 0; off >>= 1) c += __shfl_xor(c, off);
    const float inv = 0.5f / (float)c;

    const int QMB[NQ] = {0,0,0,0,1,1,1,2,2,3};
    const int QNB[NQ] = {0,1,2,3,1,2,3,2,3,3};
    const float* rp = rpart + (size_t)cls * (NQ * 256);
#pragma unroll
    for (int q = 0; q < NQ; ++q) {
        f32x4 s = (f32x4){0.f, 0.f, 0.f, 0.f};
#pragma unroll
        for (int ch = 0; ch < CH; ++ch)
            s += *reinterpret_cast<const f32x4*>(rp + (size_t)ch * (NCLS * NQ * 256) + q * 256 + (i << 2));
        const int row0 = QMB[q] * 16 + ((i >> 4) << 2);
        const int colo = QNB[q] * 16 + (i & 15);
#pragma unroll
        for (int rr = 0; rr < 4; ++rr) {
            M[row0 + rr][colo] = s[rr];
            M[colo][row0 + rr] = s[rr];
        }
    }
    __syncthreads();

    float row[64];
#pragma unroll
    for (int c2 = 0; c2 < 64; ++c2)
        row[c2] = M[i][c2] * inv + (c2 == i ? 1.0f : 0.0f);

#pragma unroll
    for (int j = 0; j < 64; ++j) {
        const float piv = __shfl(row[j], j);
        const float li  = row[j] * rsqrtf(piv);
        lcol[i] = li;
        __syncthreads();
#pragma unroll
        for (int c2 = j + 1; c2 < 64; ++c2)
            row[c2] -= li * lcol[c2];
        __syncthreads();
    }

    float slog = 0.f;
#pragma unroll
    for (int j = 0; j < 64; ++j)
        if (i == j) slog = __logf(row[j]);
    slog += __shfl_down(slog, 32); slog += __shfl_down(slog, 16);
    slog += __shfl_down(slog, 8);  slog += __shfl_down(slog, 4);
    slog += __shfl_down(slog, 2);  slog += __shfl_down(slog, 1);
    if (i == 0) atomicAdd(out, 0.5f * slog);
}

// ---------- launcher ----------
extern "C" void kernel_launch(void* const* d_in, const int* in_sizes, int n_in,
                              void* d_out, int out_size, void* d_ws, size_t ws_size,
                              hipStream_t stream) {
    const float* h    = (const float*)d_in[0];
    const int*   yhat = (const int*)d_in[1];
    const int    N    = in_sizes[1];
    float* out = (float*)d_out;

    // ws layout: [rpart CH*100*256 f32][cntp G*16 int][partials G*PPB f32]
    const size_t rpart_sz = (size_t)CH * NCLS * NQ * 256 * sizeof(float);
    const size_t cntp_off = rpart_sz;

    const int ntiles = (N + TILE - 1) / TILE;
    int G = 256;
    {
        const size_t perG = 64 + (size_t)PPB * sizeof(float);
        if (ws_size > rpart_sz) {
            size_t maxG = (ws_size - rpart_sz) / perG;
            if ((size_t)G > maxG) G = (int)maxG;
        } else G = 1;
        if (G < 1) G = 1;
    }
    if (G > ntiles) G = ntiles;

    const size_t partials_off = cntp_off + (size_t)G * 16 * sizeof(int);
    float* rpart    = (float*)d_ws;
    int*   cntp     = (int*)((char*)d_ws + cntp_off);
    float* partials = (float*)((char*)d_ws + partials_off);

    HL_gram<<<G, TPB, 0, stream>>>(h, yhat, partials, cntp, N, ntiles, G);

    int CS = (G + CH - 1) / CH;
    const int rthreads = CH * NCLS * NQ * 64;
    HL_reduce<<<(rthreads + 255) / 256, 256, 0, stream>>>(partials, rpart, out, G, CS);

    HL_chol<<<NCLS, 64, 0, stream>>>(rpart, cntp, out, G);
}